// Round 1
// baseline (59.426 us; speedup 1.0000x reference)
//
#include <hip/hip_runtime.h>
#include <math.h>

namespace {

constexpr int D    = 32;
constexpr int DP1  = 33;
constexpr int H    = 128;
constexpr int W1S  = 129;   // padded stride: banks (i+k)%32 conflict-free both ways
constexpr int W2S  = 33;    // padded stride: banks (k+j)%32 conflict-free both ways
constexpr int WAVES   = 8;
constexpr int THREADS = WAVES * 64;
constexpr int EPW = 2;                // elements per wave
constexpr int EPB = WAVES * EPW;      // 16 elements per block

__device__ __forceinline__ float fast_tanh(float z) {
  float e = __expf(2.0f * z);                       // v_exp_f32 path
  return 1.0f - 2.0f * __builtin_amdgcn_rcpf(e + 1.0f);
}

__global__ __launch_bounds__(THREADS, 1) void fpe_loss_kernel(
    const float* __restrict__ x, const float* __restrict__ t,
    const float* __restrict__ beta, const float* __restrict__ W1,
    const float* __restrict__ b1, const float* __restrict__ W2,
    const float* __restrict__ b2, float* __restrict__ out, int Btot)
{
  __shared__ float W1p[DP1 * W1S];   // W1p[i*129 + k]
  __shared__ float W2p[H * W2S];     // W2p[k*33 + j]
  __shared__ float scr[WAVES][512];  // per-wave scratch

  const int tid = threadIdx.x;
  // Stage weights: coalesced global reads, conflict-free LDS writes.
  for (int n = tid; n < DP1 * H; n += THREADS) {
    int i = n >> 7, k = n & (H - 1);
    W1p[i * W1S + k] = W1[n];
  }
  for (int n = tid; n < H * D; n += THREADS) {
    int k = n >> 5, j = n & (D - 1);
    W2p[k * W2S + j] = W2[n];
  }
  __syncthreads();

  const int wave = tid >> 6;
  const int lane = tid & 63;
  float* Sc   = scr[wave];
  float* u_s  = Sc;         // 34: [x(32), t, pad]
  float* sv_s = Sc + 34;    // 32: s
  float* dt_s = Sc + 66;    // 32: ds/dt
  float* h_s  = Sc + 128;   // 128
  float* r_s  = Sc + 256;   // 128: g * W1[32,k]
  float* q_s  = Sc + 384;   // 128

  const int k0 = lane, k1 = lane + 64;

  for (int e = 0; e < EPW; ++e) {
    const int b = blockIdx.x * EPB + wave * EPW + e;
    const bool valid = (b < Btot);

    if (valid) {
      if (lane < D)       u_s[lane] = x[b * D + lane];
      else if (lane == D) u_s[D]    = t[b];
    }
    __syncthreads();

    // Phase 1: z, h, g, r  (lane owns hidden units k0, k1)
    float h0 = 0, h1 = 0, g0 = 0, g1 = 0;
    if (valid) {
      float z0 = b1[k0], z1 = b1[k1];
      #pragma unroll
      for (int i = 0; i < DP1; ++i) {
        float ui = u_s[i];
        z0 = fmaf(W1p[i * W1S + k0], ui, z0);
        z1 = fmaf(W1p[i * W1S + k1], ui, z1);
      }
      h0 = fast_tanh(z0); h1 = fast_tanh(z1);
      g0 = 1.0f - h0 * h0; g1 = 1.0f - h1 * h1;
      h_s[k0] = h0; h_s[k1] = h1;
      r_s[k0] = g0 * W1p[32 * W1S + k0];
      r_s[k1] = g1 * W1p[32 * W1S + k1];
    }
    __syncthreads();

    // Phase 2: lanes<32 -> s_j = b2 + W2^T h ; lanes>=32 -> dsdt_j = W2^T r
    if (valid) {
      const int j = lane & 31;
      const float* vec = (lane < 32) ? h_s : r_s;
      float a0 = (lane < 32) ? b2[j] : 0.0f;
      float a1 = 0, a2 = 0, a3 = 0;
      #pragma unroll
      for (int k = 0; k < H; k += 4) {
        a0 = fmaf(W2p[(k + 0) * W2S + j], vec[k + 0], a0);
        a1 = fmaf(W2p[(k + 1) * W2S + j], vec[k + 1], a1);
        a2 = fmaf(W2p[(k + 2) * W2S + j], vec[k + 2], a2);
        a3 = fmaf(W2p[(k + 3) * W2S + j], vec[k + 3], a3);
      }
      float acc = (a0 + a1) + (a2 + a3);
      if (lane < 32) sv_s[j] = acc; else dt_s[j] = acc;
    }
    __syncthreads();

    // Phase 3: q_k = g*(m - 2*c*h), m = sum_j W2[k,j]*(2 s_j + x_j),
    //          c = sum_j W1[j,k]*W2[k,j]
    if (valid) {
      float m0 = 0, m1 = 0, c0 = 0, c1 = 0;
      #pragma unroll
      for (int j = 0; j < D; ++j) {
        float v   = 2.0f * sv_s[j] + u_s[j];
        float w20 = W2p[k0 * W2S + j];
        float w21 = W2p[k1 * W2S + j];
        m0 = fmaf(w20, v, m0);
        m1 = fmaf(w21, v, m1);
        c0 = fmaf(W1p[j * W1S + k0], w20, c0);
        c1 = fmaf(W1p[j * W1S + k1], w21, c1);
      }
      q_s[k0] = g0 * (m0 - 2.0f * c0 * h0);
      q_s[k1] = g1 * (m1 - 2.0f * c1 * h1);
    }
    __syncthreads();

    // Phase 4: grad_j = s_j + sum_k W1[j,k] q_k ; resid; L1-mean over j
    if (valid) {
      const int j    = lane & 31;
      const int koff = (lane >> 5) << 6;   // halves of k split across lane groups
      float a0 = 0, a1 = 0, a2 = 0, a3 = 0;
      #pragma unroll
      for (int kk = 0; kk < 64; kk += 4) {
        a0 = fmaf(W1p[j * W1S + koff + kk + 0], q_s[koff + kk + 0], a0);
        a1 = fmaf(W1p[j * W1S + koff + kk + 1], q_s[koff + kk + 1], a1);
        a2 = fmaf(W1p[j * W1S + koff + kk + 2], q_s[koff + kk + 2], a2);
        a3 = fmaf(W1p[j * W1S + koff + kk + 3], q_s[koff + kk + 3], a3);
      }
      float acc = (a0 + a1) + (a2 + a3);
      acc += __shfl_xor(acc, 32);          // combine k-halves
      float grad  = sv_s[j] + acc;
      float resid = dt_s[j] - 0.5f * beta[b] * grad;
      float a = fabsf(resid);
      a += __shfl_xor(a, 1);
      a += __shfl_xor(a, 2);
      a += __shfl_xor(a, 4);
      a += __shfl_xor(a, 8);
      a += __shfl_xor(a, 16);
      if (lane == 0) out[b] = a * (1.0f / 32.0f);
    }
    __syncthreads();
  }
}

} // namespace

extern "C" void kernel_launch(void* const* d_in, const int* in_sizes, int n_in,
                              void* d_out, int out_size, void* d_ws, size_t ws_size,
                              hipStream_t stream) {
  const float* x    = (const float*)d_in[0];
  const float* t    = (const float*)d_in[1];
  const float* beta = (const float*)d_in[2];
  const float* W1   = (const float*)d_in[3];
  const float* b1   = (const float*)d_in[4];
  const float* W2   = (const float*)d_in[5];
  const float* b2   = (const float*)d_in[6];
  float* out = (float*)d_out;

  const int Btot = in_sizes[1];            // t is [B,1]
  const int grid = (Btot + EPB - 1) / EPB;
  hipLaunchKernelGGL(fpe_loss_kernel, dim3(grid), dim3(THREADS), 0, stream,
                     x, t, beta, W1, b1, W2, b2, out, Btot);
}

// Round 2
// 40.767 us; speedup vs baseline: 1.4577x; 1.4577x over previous
//
#include <hip/hip_runtime.h>
#include <math.h>

namespace {

constexpr int D   = 32;
constexpr int H   = 128;
constexpr int WS  = 36;    // padded row stride (floats) for W1T / W2r; 144 B, 16-B aligned
constexpr int HS  = 132;   // h-buffer stride per element (pad 4 -> 2-way banks max)
constexpr int THREADS = 128;  // 2 waves
constexpr int EPB = 32;       // elements per block (4 lanes each)

__device__ __forceinline__ float fast_tanh(float z) {
  float e = __expf(2.0f * z);
  return 1.0f - 2.0f * __builtin_amdgcn_rcpf(e + 1.0f);
}

__global__ __launch_bounds__(THREADS, 1) void fpe_kernel(
    const float* __restrict__ xg, const float* __restrict__ tg,
    const float* __restrict__ betag, const float* __restrict__ W1g,
    const float* __restrict__ b1g, const float* __restrict__ W2g,
    const float* __restrict__ b2g, float* __restrict__ out, int Btot)
{
  __shared__ float W1T[H * WS];    // W1T[k][i], i<33; [33]=b1_k, [34]=c_k
  __shared__ float W2r[H * WS];    // W2r[k][j], j<32
  __shared__ float hbuf[EPB * HS]; // per-element h cache
  __shared__ float b2s[D];

  const int tid = threadIdx.x;
  const int e   = tid >> 2;
  const int kq  = tid & 3;
  const int b   = blockIdx.x * EPB + e;
  const bool valid = (b < Btot);
  const int bc = valid ? b : (Btot - 1);

  // ---- issue per-element global loads first (latency hidden under staging)
  float4 xr[8];
  const float4* xv = reinterpret_cast<const float4*>(xg + (size_t)bc * D);
  #pragma unroll
  for (int q = 0; q < 8; ++q) xr[q] = xv[q];
  const float tval = tg[bc];
  const float hb   = 0.5f * betag[bc];

  // ---- stage weights (transposed W1), biases
  for (int n = tid; n < 33 * H; n += THREADS) {
    int i = n >> 7, k = n & (H - 1);
    W1T[k * WS + i] = W1g[n];
  }
  for (int n = tid; n < H * D; n += THREADS) {
    int k = n >> 5, j = n & (D - 1);
    W2r[k * WS + j] = W2g[n];
  }
  if (tid < H) W1T[tid * WS + 33] = b1g[tid];
  if (tid < D) b2s[tid] = b2g[tid];
  __syncthreads();

  // c_k = sum_j W1[j,k] * W2[k,j]  (batch-independent), pack next to b1
  if (tid < H) {
    const float* wa = W1T + tid * WS;
    const float* wb = W2r + tid * WS;
    float c0 = 0, c1 = 0, c2 = 0, c3 = 0;
    #pragma unroll
    for (int j = 0; j < D; j += 4) {
      c0 = fmaf(wa[j + 0], wb[j + 0], c0);
      c1 = fmaf(wa[j + 1], wb[j + 1], c1);
      c2 = fmaf(wa[j + 2], wb[j + 2], c2);
      c3 = fmaf(wa[j + 3], wb[j + 3], c3);
    }
    W1T[tid * WS + 34] = (c0 + c1) + (c2 + c3);
  }
  __syncthreads();

  // ---- unpack x
  float x[D];
  #pragma unroll
  for (int q = 0; q < 8; ++q) {
    x[4*q+0] = xr[q].x; x[4*q+1] = xr[q].y; x[4*q+2] = xr[q].z; x[4*q+3] = xr[q].w;
  }

  float ps[D], pd[D];
  #pragma unroll
  for (int j = 0; j < D; ++j) { ps[j] = 0.0f; pd[j] = 0.0f; }

  float* hrow = hbuf + e * HS + kq;

  // ================= Pass A: z, h, partial s and ds/dt over this lane's k's
  #pragma unroll 2
  for (int n = 0; n < 32; ++n) {
    const int k = 4 * n + kq;
    const float4* wa = reinterpret_cast<const float4*>(W1T + k * WS);
    const float4* wb = reinterpret_cast<const float4*>(W2r + k * WS);
    float4 a[9];
    #pragma unroll
    for (int q = 0; q < 9; ++q) a[q] = wa[q];

    float z0 = a[8].y, z1 = 0.0f, z2 = 0.0f, z3 = 0.0f;  // a[8].y = b1_k
    #pragma unroll
    for (int q = 0; q < 8; ++q) {
      z0 = fmaf(a[q].x, x[4*q+0], z0);
      z1 = fmaf(a[q].y, x[4*q+1], z1);
      z2 = fmaf(a[q].z, x[4*q+2], z2);
      z3 = fmaf(a[q].w, x[4*q+3], z3);
    }
    const float w1t = a[8].x;                            // W1[32,k]
    float z = ((z0 + z1) + (z2 + z3)) + w1t * tval;
    float hh = fast_tanh(z);
    hrow[4 * n] = hh;
    float g = 1.0f - hh * hh;
    float r = g * w1t;
    #pragma unroll
    for (int q = 0; q < 8; ++q) {
      float4 w2 = wb[q];
      ps[4*q+0] = fmaf(w2.x, hh, ps[4*q+0]);
      ps[4*q+1] = fmaf(w2.y, hh, ps[4*q+1]);
      ps[4*q+2] = fmaf(w2.z, hh, ps[4*q+2]);
      ps[4*q+3] = fmaf(w2.w, hh, ps[4*q+3]);
      pd[4*q+0] = fmaf(w2.x, r,  pd[4*q+0]);
      pd[4*q+1] = fmaf(w2.y, r,  pd[4*q+1]);
      pd[4*q+2] = fmaf(w2.z, r,  pd[4*q+2]);
      pd[4*q+3] = fmaf(w2.w, r,  pd[4*q+3]);
    }
  }

  // ---- reduce s, dsdt across the 4 k-quarter lanes (quad-perm DPP shuffles)
  #pragma unroll
  for (int j = 0; j < D; ++j) {
    ps[j] += __shfl_xor(ps[j], 1);
    ps[j] += __shfl_xor(ps[j], 2);
    pd[j] += __shfl_xor(pd[j], 1);
    pd[j] += __shfl_xor(pd[j], 2);
  }

  // v = 2s + x ; A = dsdt - hb*s   (x, ps, pd die here)
  float v[D], A[D];
  #pragma unroll
  for (int q = 0; q < 8; ++q) {
    float4 bq = reinterpret_cast<const float4*>(b2s)[q];
    float s0 = ps[4*q+0] + bq.x, s1 = ps[4*q+1] + bq.y;
    float s2 = ps[4*q+2] + bq.z, s3 = ps[4*q+3] + bq.w;
    v[4*q+0] = fmaf(2.0f, s0, x[4*q+0]);
    v[4*q+1] = fmaf(2.0f, s1, x[4*q+1]);
    v[4*q+2] = fmaf(2.0f, s2, x[4*q+2]);
    v[4*q+3] = fmaf(2.0f, s3, x[4*q+3]);
    A[4*q+0] = fmaf(-hb, s0, pd[4*q+0]);
    A[4*q+1] = fmaf(-hb, s1, pd[4*q+1]);
    A[4*q+2] = fmaf(-hb, s2, pd[4*q+2]);
    A[4*q+3] = fmaf(-hb, s3, pd[4*q+3]);
  }

  // ================= Pass B: q_k and partial grad
  float pg[D];
  #pragma unroll
  for (int j = 0; j < D; ++j) pg[j] = 0.0f;

  #pragma unroll 2
  for (int n = 0; n < 32; ++n) {
    const int k = 4 * n + kq;
    const float4* wa = reinterpret_cast<const float4*>(W1T + k * WS);
    const float4* wb = reinterpret_cast<const float4*>(W2r + k * WS);
    float4 w2[8];
    #pragma unroll
    for (int q = 0; q < 8; ++q) w2[q] = wb[q];

    float m0 = 0, m1 = 0, m2 = 0, m3 = 0;
    #pragma unroll
    for (int q = 0; q < 8; ++q) {
      m0 = fmaf(w2[q].x, v[4*q+0], m0);
      m1 = fmaf(w2[q].y, v[4*q+1], m1);
      m2 = fmaf(w2[q].z, v[4*q+2], m2);
      m3 = fmaf(w2[q].w, v[4*q+3], m3);
    }
    float m = (m0 + m1) + (m2 + m3);

    float hh = hrow[4 * n];
    float g  = 1.0f - hh * hh;
    float c  = wa[8].z;                       // c_k
    float qk = g * fmaf(-2.0f * c, hh, m);

    #pragma unroll
    for (int q = 0; q < 8; ++q) {
      float4 a = wa[q];
      pg[4*q+0] = fmaf(a.x, qk, pg[4*q+0]);
      pg[4*q+1] = fmaf(a.y, qk, pg[4*q+1]);
      pg[4*q+2] = fmaf(a.z, qk, pg[4*q+2]);
      pg[4*q+3] = fmaf(a.w, qk, pg[4*q+3]);
    }
  }

  // ---- reduce grad, compute L1 mean
  #pragma unroll
  for (int j = 0; j < D; ++j) {
    pg[j] += __shfl_xor(pg[j], 1);
    pg[j] += __shfl_xor(pg[j], 2);
  }
  float acc = 0.0f;
  #pragma unroll
  for (int j = 0; j < D; ++j) acc += fabsf(fmaf(-hb, pg[j], A[j]));

  if (valid && kq == 0) out[b] = acc * (1.0f / 32.0f);
}

} // namespace

extern "C" void kernel_launch(void* const* d_in, const int* in_sizes, int n_in,
                              void* d_out, int out_size, void* d_ws, size_t ws_size,
                              hipStream_t stream) {
  const float* x    = (const float*)d_in[0];
  const float* t    = (const float*)d_in[1];
  const float* beta = (const float*)d_in[2];
  const float* W1   = (const float*)d_in[3];
  const float* b1   = (const float*)d_in[4];
  const float* W2   = (const float*)d_in[5];
  const float* b2   = (const float*)d_in[6];
  float* out = (float*)d_out;

  const int Btot = in_sizes[1];  // t is [B,1]
  const int grid = (Btot + EPB - 1) / EPB;
  hipLaunchKernelGGL(fpe_kernel, dim3(grid), dim3(THREADS), 0, stream,
                     x, t, beta, W1, b1, W2, b2, out, Btot);
}